// Round 1
// baseline (239.562 us; speedup 1.0000x reference)
//
#include <hip/hip_runtime.h>

#define HW   192
#define HW2  (HW*HW)
#define NPIX (2*HW2)   // B*H*W
#define NUP  (HW*4)

__device__ __forceinline__ float clamp255f(float v){ return fminf(fmaxf(v,0.f),255.f); }

// ---------------------------------------------------------------------------
// Simplex LUT interpolation for one 4-vector v (pre-clip), branch-free path
// select between LSB (w1, Q=16, relative-offset indexing) and MSB (w2, Q=64).
// ---------------------------------------------------------------------------
template<int OUTC>
__device__ __forceinline__ void interp_eval(const float* v4,
    const float* __restrict__ w1m, const float* __restrict__ w2m, float* out)
{
  float f1[4], f2[4]; int i1[4], i2[4];
#pragma unroll
  for (int k=0;k<4;k++){
    float vk = clamp255f(v4[k]);
    int a = (int)(vk*0.0625f);   a = a>15?15:a;   // floor(v/16), clip L1-2
    int b = (int)(vk*0.015625f); b = b>3 ?3 :b;   // floor(v/64), clip L2-2
    i1[k]=a; f1[k]=vk-(float)a*16.f;
    i2[k]=b; f2[k]=vk-(float)b*64.f;
  }
  const int d1=i1[1]-i1[0], d2=i1[2]-i1[0], d3=i1[3]-i1[0];
  const bool within = (d1<=1)&&(d1>=-1)&&(d2<=1)&&(d2>=-1)&&(d3<=1)&&(d3>=-1);

  float ff[4]; int ii[4];
#pragma unroll
  for (int k=0;k<4;k++){ ff[k]= within?f1[k]:f2[k]; ii[k]= within?i1[k]:i2[k]; }
  const float Q    = within?16.f:64.f;
  const float qinv = within?0.0625f:0.015625f;
  const float* tab = within? w1m : w2m;

  // stable-descending ranks (replicates stable argsort(-f))
  const int rk0 = (ff[1]> ff[0]) + (ff[2]> ff[0]) + (ff[3]> ff[0]);
  const int rk1 = (ff[0]>=ff[1]) + (ff[2]> ff[1]) + (ff[3]> ff[1]);
  const int rk2 = (ff[0]>=ff[2]) + (ff[1]>=ff[2]) + (ff[3]> ff[2]);
  const int rk3 = (ff[0]>=ff[3]) + (ff[1]>=ff[3]) + (ff[2]>=ff[3]);

  // sorted (desc) values via min/max network
  float a0=ff[0],a1=ff[1],a2=ff[2],a3=ff[3],t;
  t=fmaxf(a0,a1); a1=fminf(a0,a1); a0=t;
  t=fmaxf(a2,a3); a3=fminf(a2,a3); a2=t;
  t=fmaxf(a0,a2); a2=fminf(a0,a2); a0=t;
  t=fmaxf(a1,a3); a3=fminf(a1,a3); a1=t;
  t=fmaxf(a1,a2); a2=fminf(a1,a2); a1=t;

  float wgt[5];
  wgt[0]=(Q-a0)*qinv; wgt[1]=(a0-a1)*qinv; wgt[2]=(a1-a2)*qinv;
  wgt[3]=(a2-a3)*qinv; wgt[4]=a3*qinv;

  int idx[5];
#pragma unroll
  for (int t5=0;t5<5;t5++){
    const int c0 = rk0<t5, c1 = rk1<t5, c2 = rk2<t5, c3 = rk3<t5;
    const int A0 = ii[0]+c0;
    const int A1 = within ? (d1 + c1 - c0 + 2) : (ii[1]+c1);
    const int A2 = within ? (d2 + c2 - c0 + 2) : (ii[2]+c2);
    const int A3 = within ? (d3 + c3 - c0 + 2) : (ii[3]+c3);
    idx[t5] = A0*125 + A1*25 + A2*5 + A3;   // ref2index is arange -> linear
  }

  float s[OUTC];
#pragma unroll
  for (int c=0;c<OUTC;c++) s[c]=0.f;
#pragma unroll
  for (int t5=0;t5<5;t5++){
    const float w = wgt[t5];
    if constexpr (OUTC==16){
      const float4* row = reinterpret_cast<const float4*>(tab + (size_t)idx[t5]*16);
      float4 p0=row[0], p1=row[1], p2=row[2], p3=row[3];
      s[0]=fmaf(w,p0.x,s[0]); s[1]=fmaf(w,p0.y,s[1]); s[2]=fmaf(w,p0.z,s[2]); s[3]=fmaf(w,p0.w,s[3]);
      s[4]=fmaf(w,p1.x,s[4]); s[5]=fmaf(w,p1.y,s[5]); s[6]=fmaf(w,p1.z,s[6]); s[7]=fmaf(w,p1.w,s[7]);
      s[8]=fmaf(w,p2.x,s[8]); s[9]=fmaf(w,p2.y,s[9]); s[10]=fmaf(w,p2.z,s[10]); s[11]=fmaf(w,p2.w,s[11]);
      s[12]=fmaf(w,p3.x,s[12]); s[13]=fmaf(w,p3.y,s[13]); s[14]=fmaf(w,p3.z,s[14]); s[15]=fmaf(w,p3.w,s[15]);
    } else if constexpr (OUTC==2){
      const float2 p = reinterpret_cast<const float2*>(tab)[idx[t5]];
      s[0]=fmaf(w,p.x,s[0]); s[1]=fmaf(w,p.y,s[1]);
    } else {
      s[0]=fmaf(w, tab[idx[t5]], s[0]);
    }
  }
#pragma unroll
  for (int c=0;c<OUTC;c++) out[c]=s[c];
}

// rotated tap from the 5x5 clamped neighborhood (center at [2][2])
template<int R>
__device__ __forceinline__ float tapf(const float n[5][5], int kh, int kw){
  if constexpr (R==0) return n[2+kh][2+kw];
  else if constexpr (R==1) return n[2+kw][2-kh];
  else if constexpr (R==2) return n[2-kh][2-kw];
  else                     return n[2-kw][2+kh];
}

template<int R>
__device__ __forceinline__ void conv4r(const float n[5][5], const float* __restrict__ swm, float v[4]){
#pragma unroll
  for (int oc=0;oc<4;oc++){
    float a=0.f;
#pragma unroll
    for (int kh=0;kh<3;kh++)
#pragma unroll
      for (int kw=0;kw<3;kw++)
        a = fmaf(swm[oc*9+kh*3+kw], tapf<R>(n,kh,kw), a);
    v[oc]=a;
  }
}

__global__ void __launch_bounds__(256) quant_kernel(const float* __restrict__ x, float* __restrict__ o){
  int i = blockIdx.x*256 + threadIdx.x;
  if (i < NPIX) o[i] = rintf(clamp255f(x[i]*255.f));
}

// Stages 1-4: one thread per pixel, full (m,r) loop in reference order
// (keeps FP accumulation order identical before the round_ste quantizer).
template<int OUTC>
__global__ void __launch_bounds__(256) stage_kernel(
    const float* __restrict__ img, const float* __restrict__ sw,
    const float* __restrict__ w1,  const float* __restrict__ w2,
    const float* __restrict__ res, float* __restrict__ outA, float* __restrict__ outB)
{
  int tid = blockIdx.x*256 + threadIdx.x;
  if (tid >= NPIX) return;
  const int b = tid/HW2, rem = tid - b*HW2;
  const int y = rem/HW,  x   = rem - y*HW;
  const float* im = img + b*HW2;

  float n[5][5];
#pragma unroll
  for (int dy=0;dy<5;dy++){
    int yy = y+dy-2; yy = yy<0?0:(yy>HW-1?HW-1:yy);
#pragma unroll
    for (int dx=0;dx<5;dx++){
      int xx = x+dx-2; xx = xx<0?0:(xx>HW-1?HW-1:xx);
      n[dy][dx] = im[yy*HW+xx];
    }
  }

  float acc[OUTC];
#pragma unroll
  for (int c=0;c<OUTC;c++) acc[c]=0.f;

#pragma unroll
  for (int m=0;m<3;m++){
    const float* swm = sw + m*36;
    const float* w1m = w1 + (size_t)m*2125*OUTC;
    const float* w2m = w2 + (size_t)m*625*OUTC;
    float v[4], o[OUTC];
#define DO_ROT(R) \
    conv4r<R>(n,swm,v); interp_eval<OUTC>(v,w1m,w2m,o); \
    _Pragma("unroll") for (int c=0;c<OUTC;c++) acc[c] += (o[c] + res[m*OUTC+c]);
    DO_ROT(0) DO_ROT(1) DO_ROT(2) DO_ROT(3)
#undef DO_ROT
  }

  const float y0 = rintf(clamp255f((acc[0]/12.0f)*255.0f));
  outA[tid] = y0;
  if constexpr (OUTC==2){
    const float y1 = rintf(clamp255f((acc[1]/12.0f)*255.0f));
    outB[tid] = y1;
  }
}

// Stage 6: 4 lanes per pixel (one rotation each), loop (c outer, m inner),
// per-rotation channel permutation, quad butterfly reduce, lane r writes
// output row 4*by+r as one float4.
__global__ void __launch_bounds__(256) stage6_kernel(
    const float* __restrict__ feat, const float* __restrict__ sw,
    const float* __restrict__ w1,   const float* __restrict__ w2,
    const float* __restrict__ res,  float* __restrict__ out)
{
  int t = blockIdx.x*256 + threadIdx.x;
  const int r   = t & 3;
  const int pix = t >> 2;
  if (pix >= NPIX) return;
  const int b  = pix/HW2, rem = pix - b*HW2;
  const int by = rem/HW,  bx  = rem - by*HW;

  int yp[3],ym[3],xp[3],xm[3];
#pragma unroll
  for (int d=0; d<3; d++){
    yp[d] = by+d>HW-1?HW-1:by+d;  ym[d] = by-d<0?0:by-d;
    xp[d] = bx+d>HW-1?HW-1:bx+d;  xm[d] = bx-d<0?0:bx-d;
  }
  // 9 tap addresses within a plane (rotation folded into index select, once)
  int addr9[3][3];
#pragma unroll
  for (int kh=0;kh<3;kh++)
#pragma unroll
    for (int kw=0;kw<3;kw++){
      const int ry = (r==0)? yp[kh] : (r==1)? yp[kw] : (r==2)? ym[kh] : ym[kw];
      const int cx = (r==0)? xp[kw] : (r==1)? xm[kh] : (r==2)? xm[kw] : xp[kh];
      addr9[kh][kw] = ry*HW+cx;
    }

  float racc[16];
#pragma unroll
  for (int i=0;i<16;i++) racc[i]=0.f;

#pragma unroll
  for (int c=0;c<4;c++){
    const float* im = feat + (size_t)c*NPIX + b*HW2;
    float m3[3][3];
#pragma unroll
    for (int kh=0;kh<3;kh++)
#pragma unroll
      for (int kw=0;kw<3;kw++) m3[kh][kw] = im[addr9[kh][kw]];
#pragma unroll
    for (int m=0;m<3;m++){
      const float* swmc = sw  + (m*4+c)*36;
      const float* w1mc = w1  + (size_t)(m*4+c)*2125*16;
      const float* w2mc = w2  + (size_t)(m*4+c)*625*16;
      const float* remc = res + (m*4+c)*16;
      float v[4];
#pragma unroll
      for (int oc=0;oc<4;oc++){
        float a=0.f;
#pragma unroll
        for (int kh=0;kh<3;kh++)
#pragma unroll
          for (int kw=0;kw<3;kw++)
            a = fmaf(swmc[oc*9+kh*3+kw], m3[kh][kw], a);
        v[oc]=a;
      }
      float o[16];
      interp_eval<16>(v,w1mc,w2mc,o);
#pragma unroll
      for (int i=0;i<16;i++) racc[i] += (o[i] + remc[i]);
    }
  }

  // permute accumulated channels into output (p',q') order for this rotation
  float po[16];
  if (r==0){
#pragma unroll
    for (int i=0;i<16;i++) po[i]=racc[i];
  } else if (r==1){
#pragma unroll
    for (int p=0;p<4;p++)
#pragma unroll
      for (int q=0;q<4;q++) po[p*4+q]=racc[(3-q)*4+p];
  } else if (r==2){
#pragma unroll
    for (int p=0;p<4;p++)
#pragma unroll
      for (int q=0;q<4;q++) po[p*4+q]=racc[(3-p)*4+(3-q)];
  } else {
#pragma unroll
    for (int p=0;p<4;p++)
#pragma unroll
      for (int q=0;q<4;q++) po[p*4+q]=racc[q*4+(3-p)];
  }

  // reduce the 4 rotation-lanes of this pixel (quad butterfly)
#pragma unroll
  for (int i=0;i<16;i++){
    po[i] += __shfl_xor(po[i],1);
    po[i] += __shfl_xor(po[i],2);
  }

  float r0,r1,r2,r3;
  if (r==0){ r0=po[0];  r1=po[1];  r2=po[2];  r3=po[3];  }
  else if (r==1){ r0=po[4];  r1=po[5];  r2=po[6];  r3=po[7];  }
  else if (r==2){ r0=po[8];  r1=po[9];  r2=po[10]; r3=po[11]; }
  else          { r0=po[12]; r1=po[13]; r2=po[14]; r3=po[15]; }

  auto fin = [](float s)->float{
    const float hr = s/48.0f;
    return fminf(fmaxf(hr*255.f,0.f),255.f)/255.f;
  };
  float* op = out + (size_t)b*(NUP*NUP) + (size_t)(4*by+r)*NUP + 4*bx;
  *reinterpret_cast<float4*>(op) = make_float4(fin(r0),fin(r1),fin(r2),fin(r3));
}

extern "C" void kernel_launch(void* const* d_in, const int* in_sizes, int n_in,
                              void* d_out, int out_size, void* d_ws, size_t ws_size,
                              hipStream_t stream)
{
  const float* x       = (const float*)d_in[0];
  // d_in[1] = ref2index: arange -> indexing computed analytically, unused
  const float* samp123 = (const float*)d_in[2];
  const float* w1123   = (const float*)d_in[3];
  const float* w2123   = (const float*)d_in[4];
  const float* res123  = (const float*)d_in[5];
  const float* samp4   = (const float*)d_in[6];
  const float* w14     = (const float*)d_in[7];
  const float* w24     = (const float*)d_in[8];
  const float* res4    = (const float*)d_in[9];
  const float* samp6   = (const float*)d_in[10];
  const float* w16     = (const float*)d_in[11];
  const float* w26     = (const float*)d_in[12];
  const float* res6    = (const float*)d_in[13];

  float* ws   = (float*)d_ws;
  float* feat = ws;             // 4 planes of NPIX (refine channels 0..3)
  float* curA = ws + 4*NPIX;
  float* curB = ws + 5*NPIX;

  const int GB = NPIX/256;      // 288, exact

  quant_kernel<<<GB,256,0,stream>>>(x, curA);
  // stage strides: samp 3*4*9=108, w1 3*2125*2=12750, w2 3*625*2=3750, res 3*2=6
  stage_kernel<2><<<GB,256,0,stream>>>(curA, samp123,      w1123,        w2123,       res123,    feat,        curB);
  stage_kernel<2><<<GB,256,0,stream>>>(curB, samp123+108,  w1123+12750,  w2123+3750,  res123+6,  feat+NPIX,   curA);
  stage_kernel<2><<<GB,256,0,stream>>>(curA, samp123+216,  w1123+25500,  w2123+7500,  res123+12, feat+2*NPIX, curB);
  stage_kernel<1><<<GB,256,0,stream>>>(curB, samp4,        w14,          w24,         res4,      feat+3*NPIX, nullptr);
  stage6_kernel<<<NPIX*4/256,256,0,stream>>>(feat, samp6, w16, w26, res6, (float*)d_out);
}